// Round 6
// baseline (332.177 us; speedup 1.0000x reference)
//
#include <hip/hip_runtime.h>
#include <stdint.h>

#define NROWS 8192
#define HALF_N 4096
#define DIM 512
#define INV_TEMP 2.0f
#define E2SCALE 2.8853900817779268f  /* INV_TEMP * log2(e) */
#define LN2 0.6931471805599453f
#define NTILES 2080

typedef __bf16 bf16x8 __attribute__((ext_vector_type(8)));
typedef float f32x4 __attribute__((ext_vector_type(4)));

__device__ __forceinline__ unsigned f2bf(float f) {
  unsigned u = __float_as_uint(f);
  unsigned r = 0x7FFFu + ((u >> 16) & 1u);
  return (u + r) >> 16;  // round-to-nearest-even bf16 bits
}

// global -> LDS direct copy, 16B per lane; LDS dest is wave-uniform base + lane*16
__device__ __forceinline__ void gload_lds16(const unsigned short* g, unsigned short* l) {
  __builtin_amdgcn_global_load_lds(
      (const __attribute__((address_space(1))) unsigned int*)(uintptr_t)g,
      (__attribute__((address_space(3))) unsigned int*)(uint32_t)(uintptr_t)l,
      16, 0, 0);
}

// One wave per row: sumsq -> rsqrt -> bf16 store. Zeroes sumexp + completion counter.
__global__ void __launch_bounds__(256) k_normalize(const float* __restrict__ zi,
                                                   const float* __restrict__ zj,
                                                   unsigned short* __restrict__ zn,
                                                   float* __restrict__ sumexp,
                                                   int* __restrict__ counter) {
  int tid = threadIdx.x;
  int gid = blockIdx.x * 256 + tid;
  if (gid < NROWS) sumexp[gid] = 0.0f;
  if (gid == 0) *counter = 0;
  int wave = tid >> 6, lane = tid & 63;
  int row = blockIdx.x * 4 + wave;
  const float* src = (row < HALF_N) ? (zi + (size_t)row * DIM)
                                    : (zj + (size_t)(row - HALF_N) * DIM);
  const float4* s4 = (const float4*)src;
  float4 a = s4[lane];
  float4 b = s4[lane + 64];
  float ss = a.x * a.x + a.y * a.y + a.z * a.z + a.w * a.w +
             b.x * b.x + b.y * b.y + b.z * b.z + b.w * b.w;
#pragma unroll
  for (int off = 32; off > 0; off >>= 1) ss += __shfl_xor(ss, off, 64);
  float inv = 1.0f / fmaxf(sqrtf(ss), 1e-8f);
  uint2 oa, ob;
  oa.x = f2bf(a.x * inv) | (f2bf(a.y * inv) << 16);
  oa.y = f2bf(a.z * inv) | (f2bf(a.w * inv) << 16);
  ob.x = f2bf(b.x * inv) | (f2bf(b.y * inv) << 16);
  ob.y = f2bf(b.z * inv) | (f2bf(b.w * inv) << 16);
  unsigned short* dst = zn + (size_t)row * DIM;
  *((uint2*)(dst + lane * 4)) = oa;
  *((uint2*)(dst + 256 + lane * 4)) = ob;
}

// Upper-triangular 128x128 tiles (sim symmetric): off-diag tiles feed row- AND col-sums.
// BK=32 double-buffered (32 KB LDS -- R3's 64 KB version dropped residency to ~1 block/CU
// and regressed 4x; keep LDS <= 32 KB). XOR-swizzled granules (2-way = free).
// Last-finishing block computes the loss (counter-based; NO cooperative launch -- R4's
// hipLaunchCooperativeKernel silently failed under graph capture).
__global__ void __launch_bounds__(256) k_simsum(const unsigned short* __restrict__ zn,
                                                float* __restrict__ sumexp,
                                                float* __restrict__ posv,
                                                int* __restrict__ counter,
                                                float* __restrict__ out) {
  __shared__ __align__(16) unsigned short As[2][128 * 32];  // 2 x 8 KB
  __shared__ __align__(16) unsigned short Bs[2][128 * 32];  // 2 x 8 KB
  int tid = threadIdx.x;
  int wave = tid >> 6, lane = tid & 63;

  // triangular decode, tn-major: idx = tn(tn+1)/2 + tm, tm <= tn
  int idx = blockIdx.x;
  int tn = (int)((sqrtf(8.0f * idx + 1.0f) - 1.0f) * 0.5f);
  while (tn * (tn + 1) / 2 > idx) tn--;
  while ((tn + 1) * (tn + 2) / 2 <= idx) tn++;
  int tm = idx - tn * (tn + 1) / 2;
  int rowBase = tm * 128, colBase = tn * 128;
  int wr = (wave >> 1) * 64, wc = (wave & 1) * 64;  // wave's 64x64 quadrant
  int r15 = lane & 15, q = lane >> 4;

  // staging: wave stages 32 rows of A and B; 16B/lane; 4 lanes per 64 B row-chunk.
  // Source k-chunk XOR-swizzled by ((row>>1)&3); invariant under row+16.
  int rA = wave * 32 + (lane >> 2);
  int swzS = (rA >> 1) & 3;
  int c8 = ((lane & 3) ^ swzS) * 8;
  const unsigned short* gA0 = zn + (size_t)(rowBase + rA) * DIM + c8;
  const unsigned short* gA1 = gA0 + 16 * DIM;
  const unsigned short* gB0 = zn + (size_t)(colBase + rA) * DIM + c8;
  const unsigned short* gB1 = gB0 + 16 * DIM;
  unsigned short* lA[2] = {&As[0][wave * 1024], &As[1][wave * 1024]};
  unsigned short* lB[2] = {&Bs[0][wave * 1024], &Bs[1][wave * 1024]};

#define STAGE(b)                                  \
  do {                                            \
    gload_lds16(gA0, lA[b]);                      \
    gload_lds16(gA1, lA[b] + 512);                \
    gload_lds16(gB0, lB[b]);                      \
    gload_lds16(gB1, lB[b] + 512);                \
    gA0 += 32; gA1 += 32; gB0 += 32; gB1 += 32;   \
  } while (0)

  f32x4 acc[4][4];
#pragma unroll
  for (int i = 0; i < 4; i++)
#pragma unroll
    for (int j = 0; j < 4; j++) acc[i][j] = (f32x4){0.f, 0.f, 0.f, 0.f};

  int swzR = (r15 >> 1) & 3;
  int aIdx0 = (wr + r15) * 4 + (q ^ swzR);  // bf16x8 idx; +64 per 16-row step
  int bIdx0 = (wc + r15) * 4 + (q ^ swzR);

#define COMPUTE(b)                                                                 \
  do {                                                                             \
    const bf16x8* Av = (const bf16x8*)As[b];                                       \
    const bf16x8* Bv = (const bf16x8*)Bs[b];                                       \
    bf16x8 af[4], bfr[4];                                                          \
    _Pragma("unroll") for (int i = 0; i < 4; i++) af[i] = Av[aIdx0 + i * 64];      \
    _Pragma("unroll") for (int j = 0; j < 4; j++) bfr[j] = Bv[bIdx0 + j * 64];     \
    _Pragma("unroll") for (int i = 0; i < 4; i++)                                  \
      _Pragma("unroll") for (int j = 0; j < 4; j++)                                \
        acc[i][j] = __builtin_amdgcn_mfma_f32_16x16x32_bf16(af[i], bfr[j],         \
                                                            acc[i][j], 0, 0, 0);   \
  } while (0)

  STAGE(0);  // prologue: k-window 0
#pragma unroll
  for (int s = 0; s < 16; s += 2) {
    __syncthreads();            // drains window-s loads (in flight one full phase)
    if (s + 1 < 16) STAGE(1);   // issue window s+1 before computing s
    COMPUTE(0);
    __syncthreads();
    if (s + 2 < 16) STAGE(0);
    COMPUTE(1);
  }

  // ---- Epilogue. C/D layout: col = lane&15 (+j*16), row = q*4 + reg (+i*16). ----
  bool isDiag = (tm == tn);
  bool hasPos = (tn == tm + 32);
  int rsel = r15 & 3;
  bool diagLane = (wr == wc) && (q == (r15 >> 2));  // lane holding row==col elements

  if (isDiag && diagLane) {
#pragma unroll
    for (int i = 0; i < 4; i++) acc[i][i][rsel] = -1e30f;  // exp2 -> 0 (mask diagonal)
  }
  if (hasPos && diagLane) {
#pragma unroll
    for (int i = 0; i < 4; i++) {
      float s = acc[i][i][rsel] * INV_TEMP;
      int gr = rowBase + wr + i * 16 + r15;
      __hip_atomic_store(&posv[gr], s, __ATOMIC_RELAXED, __HIP_MEMORY_SCOPE_AGENT);
      __hip_atomic_store(&posv[gr + HALF_N], s, __ATOMIC_RELAXED, __HIP_MEMORY_SCOPE_AGENT);
    }
  }

  float rs[16], cs[4];
#pragma unroll
  for (int t = 0; t < 16; t++) rs[t] = 0.f;
#pragma unroll
  for (int t = 0; t < 4; t++) cs[t] = 0.f;
#pragma unroll
  for (int i = 0; i < 4; i++)
#pragma unroll
    for (int j = 0; j < 4; j++)
#pragma unroll
      for (int r = 0; r < 4; r++) {
        float e = __builtin_amdgcn_exp2f(acc[i][j][r] * E2SCALE);
        rs[i * 4 + r] += e;
        cs[j] += e;
      }

  // Fold-reduce rs[16] across the 16-lane r15 group; lane ends with its row's sum.
#pragma unroll
  for (int t = 0; t < 8; t++) {
    float mine = (lane & 8) ? rs[t + 8] : rs[t];
    float oth = __shfl_xor((lane & 8) ? rs[t] : rs[t + 8], 8, 64);
    rs[t] = mine + oth;
  }
#pragma unroll
  for (int t = 0; t < 4; t++) {
    float mine = (lane & 4) ? rs[t + 4] : rs[t];
    float oth = __shfl_xor((lane & 4) ? rs[t] : rs[t + 4], 4, 64);
    rs[t] = mine + oth;
  }
#pragma unroll
  for (int t = 0; t < 2; t++) {
    float mine = (lane & 2) ? rs[t + 2] : rs[t];
    float oth = __shfl_xor((lane & 2) ? rs[t] : rs[t + 2], 2, 64);
    rs[t] = mine + oth;
  }
  {
    float mine = (lane & 1) ? rs[1] : rs[0];
    float oth = __shfl_xor((lane & 1) ? rs[0] : rs[1], 1, 64);
    rs[0] = mine + oth;
  }
  int myrow = rowBase + wr + ((r15 >> 2) * 16) + q * 4 + (r15 & 3);
  atomicAdd(&sumexp[myrow], rs[0]);

  if (!isDiag) {
    // col-sums: fold across the 4 q-groups; one atomic per lane
#pragma unroll
    for (int t = 0; t < 2; t++) {
      float mine = (lane & 16) ? cs[t + 2] : cs[t];
      float oth = __shfl_xor((lane & 16) ? cs[t] : cs[t + 2], 16, 64);
      cs[t] = mine + oth;
    }
    {
      float mine = (lane & 32) ? cs[1] : cs[0];
      float oth = __shfl_xor((lane & 32) ? cs[0] : cs[1], 32, 64);
      cs[0] = mine + oth;
    }
    int myj = 2 * ((lane >> 4) & 1) + ((lane >> 5) & 1);
    atomicAdd(&sumexp[colBase + wc + myj * 16 + r15], cs[0]);
  }

  // ---- Fused finalization: last block to finish computes the loss. ----
  __threadfence();  // release our posv stores / sumexp atomics device-wide
  __shared__ int amLast;
  if (tid == 0) {
    int prev = __hip_atomic_fetch_add(counter, 1, __ATOMIC_ACQ_REL, __HIP_MEMORY_SCOPE_AGENT);
    amLast = (prev == NTILES - 1);
  }
  __syncthreads();
  if (amLast) {
    __threadfence();  // acquire side
    float p = 0.f;
    for (int r = tid; r < NROWS; r += 256) {
      float se = __hip_atomic_load(&sumexp[r], __ATOMIC_RELAXED, __HIP_MEMORY_SCOPE_AGENT);
      float pv = __hip_atomic_load(&posv[r], __ATOMIC_RELAXED, __HIP_MEMORY_SCOPE_AGENT);
      p += __builtin_amdgcn_logf(se) * LN2 - pv;
    }
#pragma unroll
    for (int off = 32; off > 0; off >>= 1) p += __shfl_xor(p, off, 64);
    __shared__ float red[4];
    if (lane == 0) red[wave] = p;
    __syncthreads();
    if (tid == 0) out[0] = (red[0] + red[1] + red[2] + red[3]) / (float)NROWS;
  }
#undef STAGE
#undef COMPUTE
}

extern "C" void kernel_launch(void* const* d_in, const int* in_sizes, int n_in,
                              void* d_out, int out_size, void* d_ws, size_t ws_size,
                              hipStream_t stream) {
  const float* zi = (const float*)d_in[0];
  const float* zj = (const float*)d_in[1];
  unsigned short* zn = (unsigned short*)d_ws;                         // 8 MB
  float* sumexp = (float*)((char*)d_ws + (size_t)NROWS * DIM * 2);    // 32 KB
  float* posv = sumexp + NROWS;                                       // 32 KB
  int* counter = (int*)(posv + NROWS);                                // 4 B
  float* out = (float*)d_out;

  hipLaunchKernelGGL(k_normalize, dim3(2048), dim3(256), 0, stream, zi, zj, zn, sumexp, counter);
  hipLaunchKernelGGL(k_simsum, dim3(NTILES), dim3(256), 0, stream, zn, sumexp, posv, counter, out);
}

// Round 7
// 113.760 us; speedup vs baseline: 2.9200x; 2.9200x over previous
//
#include <hip/hip_runtime.h>
#include <stdint.h>

#define NROWS 8192
#define HALF_N 4096
#define DIM 512
#define INV_TEMP 2.0f
#define E2SCALE 2.8853900817779268f  /* INV_TEMP * log2(e) */
#define LN2 0.6931471805599453f
#define NTILES 2080

typedef __bf16 bf16x8 __attribute__((ext_vector_type(8)));
typedef float f32x4 __attribute__((ext_vector_type(4)));

__device__ __forceinline__ unsigned f2bf(float f) {
  unsigned u = __float_as_uint(f);
  unsigned r = 0x7FFFu + ((u >> 16) & 1u);
  return (u + r) >> 16;  // round-to-nearest-even bf16 bits
}

// global -> LDS direct copy, 16B per lane; LDS dest is wave-uniform base + lane*16
__device__ __forceinline__ void gload_lds16(const unsigned short* g, unsigned short* l) {
  __builtin_amdgcn_global_load_lds(
      (const __attribute__((address_space(1))) unsigned int*)(uintptr_t)g,
      (__attribute__((address_space(3))) unsigned int*)(uint32_t)(uintptr_t)l,
      16, 0, 0);
}

// One wave per row: sumsq -> rsqrt -> bf16 store. Zeroes sumexp (ws is re-poisoned).
__global__ void __launch_bounds__(256) k_normalize(const float* __restrict__ zi,
                                                   const float* __restrict__ zj,
                                                   unsigned short* __restrict__ zn,
                                                   float* __restrict__ sumexp) {
  int tid = threadIdx.x;
  int gid = blockIdx.x * 256 + tid;
  if (gid < NROWS) sumexp[gid] = 0.0f;
  int wave = tid >> 6, lane = tid & 63;
  int row = blockIdx.x * 4 + wave;
  const float* src = (row < HALF_N) ? (zi + (size_t)row * DIM)
                                    : (zj + (size_t)(row - HALF_N) * DIM);
  const float4* s4 = (const float4*)src;
  float4 a = s4[lane];
  float4 b = s4[lane + 64];
  float ss = a.x * a.x + a.y * a.y + a.z * a.z + a.w * a.w +
             b.x * b.x + b.y * b.y + b.z * b.z + b.w * b.w;
#pragma unroll
  for (int off = 32; off > 0; off >>= 1) ss += __shfl_xor(ss, off, 64);
  float inv = 1.0f / fmaxf(sqrtf(ss), 1e-8f);
  uint2 oa, ob;
  oa.x = f2bf(a.x * inv) | (f2bf(a.y * inv) << 16);
  oa.y = f2bf(a.z * inv) | (f2bf(a.w * inv) << 16);
  ob.x = f2bf(b.x * inv) | (f2bf(b.y * inv) << 16);
  ob.y = f2bf(b.z * inv) | (f2bf(b.w * inv) << 16);
  unsigned short* dst = zn + (size_t)row * DIM;
  *((uint2*)(dst + lane * 4)) = oa;
  *((uint2*)(dst + 256 + lane * 4)) = ob;
}

// Upper-triangular 128x128 tiles (sim symmetric): off-diag tiles feed row- AND col-sums.
// BK=32 double-buffered, 32 KB LDS (5 blocks/CU). XOR-swizzled granules (2-way = free).
// NO per-block device-scope fence (R4/R5: per-block __threadfence caused an L2-writeback
// storm, 5x regression). Visibility to k_final comes from kernel-boundary release.
__global__ void __launch_bounds__(256) k_simsum(const unsigned short* __restrict__ zn,
                                                float* __restrict__ sumexp,
                                                float* __restrict__ posv) {
  __shared__ __align__(16) unsigned short As[2][128 * 32];  // 2 x 8 KB
  __shared__ __align__(16) unsigned short Bs[2][128 * 32];  // 2 x 8 KB
  int tid = threadIdx.x;
  int wave = tid >> 6, lane = tid & 63;

  // triangular decode, tn-major: idx = tn(tn+1)/2 + tm, tm <= tn
  int idx = blockIdx.x;
  int tn = (int)((sqrtf(8.0f * idx + 1.0f) - 1.0f) * 0.5f);
  while (tn * (tn + 1) / 2 > idx) tn--;
  while ((tn + 1) * (tn + 2) / 2 <= idx) tn++;
  int tm = idx - tn * (tn + 1) / 2;
  int rowBase = tm * 128, colBase = tn * 128;
  int wr = (wave >> 1) * 64, wc = (wave & 1) * 64;  // wave's 64x64 quadrant
  int r15 = lane & 15, q = lane >> 4;

  // staging: wave stages 32 rows of A and B; 16B/lane; 4 lanes per 64 B row-chunk.
  // Source k-chunk XOR-swizzled by ((row>>1)&3); invariant under row+16.
  int rA = wave * 32 + (lane >> 2);
  int swzS = (rA >> 1) & 3;
  int c8 = ((lane & 3) ^ swzS) * 8;
  const unsigned short* gA0 = zn + (size_t)(rowBase + rA) * DIM + c8;
  const unsigned short* gA1 = gA0 + 16 * DIM;
  const unsigned short* gB0 = zn + (size_t)(colBase + rA) * DIM + c8;
  const unsigned short* gB1 = gB0 + 16 * DIM;
  unsigned short* lA[2] = {&As[0][wave * 1024], &As[1][wave * 1024]};
  unsigned short* lB[2] = {&Bs[0][wave * 1024], &Bs[1][wave * 1024]};

#define STAGE(b)                                  \
  do {                                            \
    gload_lds16(gA0, lA[b]);                      \
    gload_lds16(gA1, lA[b] + 512);                \
    gload_lds16(gB0, lB[b]);                      \
    gload_lds16(gB1, lB[b] + 512);                \
    gA0 += 32; gA1 += 32; gB0 += 32; gB1 += 32;   \
  } while (0)

  f32x4 acc[4][4];
#pragma unroll
  for (int i = 0; i < 4; i++)
#pragma unroll
    for (int j = 0; j < 4; j++) acc[i][j] = (f32x4){0.f, 0.f, 0.f, 0.f};

  int swzR = (r15 >> 1) & 3;
  int aIdx0 = (wr + r15) * 4 + (q ^ swzR);  // bf16x8 idx; +64 per 16-row step
  int bIdx0 = (wc + r15) * 4 + (q ^ swzR);

#define COMPUTE(b)                                                                 \
  do {                                                                             \
    const bf16x8* Av = (const bf16x8*)As[b];                                       \
    const bf16x8* Bv = (const bf16x8*)Bs[b];                                       \
    bf16x8 af[4], bfr[4];                                                          \
    _Pragma("unroll") for (int i = 0; i < 4; i++) af[i] = Av[aIdx0 + i * 64];      \
    _Pragma("unroll") for (int j = 0; j < 4; j++) bfr[j] = Bv[bIdx0 + j * 64];     \
    _Pragma("unroll") for (int i = 0; i < 4; i++)                                  \
      _Pragma("unroll") for (int j = 0; j < 4; j++)                                \
        acc[i][j] = __builtin_amdgcn_mfma_f32_16x16x32_bf16(af[i], bfr[j],         \
                                                            acc[i][j], 0, 0, 0);   \
  } while (0)

  STAGE(0);  // prologue: k-window 0
#pragma unroll
  for (int s = 0; s < 16; s += 2) {
    __syncthreads();            // drains window-s loads (in flight one full phase)
    if (s + 1 < 16) STAGE(1);   // issue window s+1 before computing s
    COMPUTE(0);
    __syncthreads();
    if (s + 2 < 16) STAGE(0);
    COMPUTE(1);
  }

  // ---- Epilogue. C/D layout: col = lane&15 (+j*16), row = q*4 + reg (+i*16). ----
  bool isDiag = (tm == tn);
  bool hasPos = (tn == tm + 32);
  int rsel = r15 & 3;
  bool diagLane = (wr == wc) && (q == (r15 >> 2));  // lane holding row==col elements

  if (isDiag && diagLane) {
#pragma unroll
    for (int i = 0; i < 4; i++) acc[i][i][rsel] = -1e30f;  // exp2 -> 0 (mask diagonal)
  }
  if (hasPos && diagLane) {
#pragma unroll
    for (int i = 0; i < 4; i++) {
      float s = acc[i][i][rsel] * INV_TEMP;
      int gr = rowBase + wr + i * 16 + r15;
      posv[gr] = s;            // unique (row,col) across grid -> race-free plain store
      posv[gr + HALF_N] = s;   // sim symmetric
    }
  }

  float rs[16], cs[4];
#pragma unroll
  for (int t = 0; t < 16; t++) rs[t] = 0.f;
#pragma unroll
  for (int t = 0; t < 4; t++) cs[t] = 0.f;
#pragma unroll
  for (int i = 0; i < 4; i++)
#pragma unroll
    for (int j = 0; j < 4; j++)
#pragma unroll
      for (int r = 0; r < 4; r++) {
        float e = __builtin_amdgcn_exp2f(acc[i][j][r] * E2SCALE);
        rs[i * 4 + r] += e;
        cs[j] += e;
      }

  // Fold-reduce rs[16] across the 16-lane r15 group; lane ends with its row's sum.
#pragma unroll
  for (int t = 0; t < 8; t++) {
    float mine = (lane & 8) ? rs[t + 8] : rs[t];
    float oth = __shfl_xor((lane & 8) ? rs[t] : rs[t + 8], 8, 64);
    rs[t] = mine + oth;
  }
#pragma unroll
  for (int t = 0; t < 4; t++) {
    float mine = (lane & 4) ? rs[t + 4] : rs[t];
    float oth = __shfl_xor((lane & 4) ? rs[t] : rs[t + 4], 4, 64);
    rs[t] = mine + oth;
  }
#pragma unroll
  for (int t = 0; t < 2; t++) {
    float mine = (lane & 2) ? rs[t + 2] : rs[t];
    float oth = __shfl_xor((lane & 2) ? rs[t] : rs[t + 2], 2, 64);
    rs[t] = mine + oth;
  }
  {
    float mine = (lane & 1) ? rs[1] : rs[0];
    float oth = __shfl_xor((lane & 1) ? rs[0] : rs[1], 1, 64);
    rs[0] = mine + oth;
  }
  int myrow = rowBase + wr + q * 4 + ((r15 >> 2) * 16) + (r15 & 3);
  atomicAdd(&sumexp[myrow], rs[0]);

  if (!isDiag) {
    // col-sums: fold across the 4 q-groups; one atomic per lane
#pragma unroll
    for (int t = 0; t < 2; t++) {
      float mine = (lane & 16) ? cs[t + 2] : cs[t];
      float oth = __shfl_xor((lane & 16) ? cs[t] : cs[t + 2], 16, 64);
      cs[t] = mine + oth;
    }
    {
      float mine = (lane & 32) ? cs[1] : cs[0];
      float oth = __shfl_xor((lane & 32) ? cs[0] : cs[1], 32, 64);
      cs[0] = mine + oth;
    }
    int myj = 2 * ((lane >> 4) & 1) + ((lane >> 5) & 1);
    atomicAdd(&sumexp[colBase + wc + myj * 16 + r15], cs[0]);
  }
#undef STAGE
#undef COMPUTE
}

__global__ void __launch_bounds__(1024) k_final(const float* __restrict__ sumexp,
                                                const float* __restrict__ posv,
                                                float* __restrict__ out) {
  __shared__ float red[16];
  int tid = threadIdx.x;
  const float4* se4 = (const float4*)sumexp;
  const float4* pv4 = (const float4*)posv;
  float p = 0.f;
#pragma unroll
  for (int c = 0; c < 2; c++) {
    float4 se = se4[tid * 2 + c];
    float4 pv = pv4[tid * 2 + c];
    p += (__builtin_amdgcn_logf(se.x) + __builtin_amdgcn_logf(se.y) +
          __builtin_amdgcn_logf(se.z) + __builtin_amdgcn_logf(se.w)) * LN2 -
         (pv.x + pv.y + pv.z + pv.w);
  }
#pragma unroll
  for (int off = 32; off > 0; off >>= 1) p += __shfl_xor(p, off, 64);
  int wv = tid >> 6, ln = tid & 63;
  if (ln == 0) red[wv] = p;
  __syncthreads();
  if (tid == 0) {
    float t = 0.f;
    for (int w = 0; w < 16; w++) t += red[w];
    out[0] = t / (float)NROWS;
  }
}

extern "C" void kernel_launch(void* const* d_in, const int* in_sizes, int n_in,
                              void* d_out, int out_size, void* d_ws, size_t ws_size,
                              hipStream_t stream) {
  const float* zi = (const float*)d_in[0];
  const float* zj = (const float*)d_in[1];
  unsigned short* zn = (unsigned short*)d_ws;                         // 8 MB
  float* sumexp = (float*)((char*)d_ws + (size_t)NROWS * DIM * 2);    // 32 KB
  float* posv = sumexp + NROWS;                                       // 32 KB
  float* out = (float*)d_out;

  hipLaunchKernelGGL(k_normalize, dim3(2048), dim3(256), 0, stream, zi, zj, zn, sumexp);
  hipLaunchKernelGGL(k_simsum, dim3(NTILES), dim3(256), 0, stream, zn, sumexp, posv);
  hipLaunchKernelGGL(k_final, dim3(1), dim3(1024), 0, stream, sumexp, posv, out);
}

// Round 8
// 96.444 us; speedup vs baseline: 3.4442x; 1.1795x over previous
//
#include <hip/hip_runtime.h>
#include <stdint.h>

#define NROWS 8192
#define HALF_N 4096
#define DIM 512          /* elements per row; == bytes per row in fp8 */
#define INV_TEMP 2.0f
#define E2SCALE 2.8853900817779268f  /* INV_TEMP * log2(e) */
#define LN2 0.6931471805599453f
#define NTILES 2080

typedef int i32x8 __attribute__((ext_vector_type(8)));
typedef float f32x16 __attribute__((ext_vector_type(16)));

// global -> LDS direct copy, 16B per lane; LDS dest is wave-uniform base + lane*16
__device__ __forceinline__ void gload_lds16(const unsigned char* g, unsigned char* l) {
  __builtin_amdgcn_global_load_lds(
      (const __attribute__((address_space(1))) unsigned int*)(uintptr_t)g,
      (__attribute__((address_space(3))) unsigned int*)(uint32_t)(uintptr_t)l,
      16, 0, 0);
}

// One wave per row: sumsq -> rsqrt -> fp8 e4m3 store (4 MB). Zeroes sumexp.
__global__ void __launch_bounds__(256) k_normalize(const float* __restrict__ zi,
                                                   const float* __restrict__ zj,
                                                   unsigned char* __restrict__ zn,
                                                   float* __restrict__ sumexp) {
  int tid = threadIdx.x;
  int gid = blockIdx.x * 256 + tid;
  if (gid < NROWS) sumexp[gid] = 0.0f;
  int wave = tid >> 6, lane = tid & 63;
  int row = blockIdx.x * 4 + wave;
  const float* src = (row < HALF_N) ? (zi + (size_t)row * DIM)
                                    : (zj + (size_t)(row - HALF_N) * DIM);
  const float4* s4 = (const float4*)src;
  float4 a = s4[lane];        // cols 4*lane .. +3
  float4 b = s4[lane + 64];   // cols 256+4*lane .. +3
  float ss = a.x * a.x + a.y * a.y + a.z * a.z + a.w * a.w +
             b.x * b.x + b.y * b.y + b.z * b.z + b.w * b.w;
#pragma unroll
  for (int off = 32; off > 0; off >>= 1) ss += __shfl_xor(ss, off, 64);
  float inv = 1.0f / fmaxf(sqrtf(ss), 1e-8f);
  int w0 = __builtin_amdgcn_cvt_pk_fp8_f32(a.x * inv, a.y * inv, 0, false);
  w0 = __builtin_amdgcn_cvt_pk_fp8_f32(a.z * inv, a.w * inv, w0, true);
  int w1 = __builtin_amdgcn_cvt_pk_fp8_f32(b.x * inv, b.y * inv, 0, false);
  w1 = __builtin_amdgcn_cvt_pk_fp8_f32(b.z * inv, b.w * inv, w1, true);
  unsigned char* dst = zn + (size_t)row * DIM;
  *((int*)(dst + lane * 4)) = w0;
  *((int*)(dst + 256 + lane * 4)) = w1;
}

// Upper-triangular 128x128 tiles (sim symmetric): off-diag tiles feed row- AND col-sums.
// MX-fp8 32x32x64 MFMA (scales = 2^0): 2x rate over bf16, half the staging bytes,
// 8 k-windows (BK=64 B) double-buffered in the SAME 32 KB LDS (occupancy lesson from
// R3: never exceed 32 KB). Same 64-B-row / 4-granule XOR swizzle as the bf16 version.
// No per-block device fences (R5 lesson: L2-writeback storm).
__global__ void __launch_bounds__(256) k_simsum(const unsigned char* __restrict__ zn,
                                                float* __restrict__ sumexp,
                                                float* __restrict__ posv) {
  __shared__ __align__(16) unsigned char As[2][128 * 64];  // 2 x 8 KB
  __shared__ __align__(16) unsigned char Bs[2][128 * 64];  // 2 x 8 KB
  int tid = threadIdx.x;
  int wave = tid >> 6, lane = tid & 63;

  // triangular decode, tn-major: idx = tn(tn+1)/2 + tm, tm <= tn
  int idx = blockIdx.x;
  int tn = (int)((sqrtf(8.0f * idx + 1.0f) - 1.0f) * 0.5f);
  while (tn * (tn + 1) / 2 > idx) tn--;
  while ((tn + 1) * (tn + 2) / 2 <= idx) tn++;
  int tm = idx - tn * (tn + 1) / 2;
  int rowBase = tm * 128, colBase = tn * 128;
  int wr = (wave >> 1) * 64, wc = (wave & 1) * 64;  // wave's 64x64 quadrant
  int h = lane >> 5, c32 = lane & 31;               // k-half and matrix row/col in 32-block

  // staging: wave stages 32 rows of A and B per window; 16B/lane; 4 lanes per 64-B row.
  // Physical granule p of row r holds source k-chunk p ^ ((r>>1)&3).
  int rA = wave * 32 + (lane >> 2);
  int chunk = (lane & 3) ^ ((rA >> 1) & 3);
  const unsigned char* gA = zn + (size_t)(rowBase + rA) * DIM + chunk * 16;
  const unsigned char* gB = zn + (size_t)(colBase + rA) * DIM + chunk * 16;
  unsigned char* lA[2] = {&As[0][wave * 2048], &As[1][wave * 2048]};
  unsigned char* lB[2] = {&Bs[0][wave * 2048], &Bs[1][wave * 2048]};

#define STAGE(b)                                  \
  do {                                            \
    gload_lds16(gA, lA[b]);                       \
    gload_lds16(gA + 16 * DIM, lA[b] + 1024);     \
    gload_lds16(gB, lB[b]);                       \
    gload_lds16(gB + 16 * DIM, lB[b] + 1024);     \
    gA += 64; gB += 64;                           \
  } while (0)

  f32x16 acc[2][2];
#pragma unroll
  for (int i = 0; i < 2; i++)
#pragma unroll
    for (int j = 0; j < 2; j++)
#pragma unroll
      for (int r = 0; r < 16; r++) acc[i][j][r] = 0.f;

  // Fragment read indices (int4 = one 16-B granule; row r at granule r*4).
  // Lane (c32,h) needs row-bytes k = h*32 + 0..31 -> granules 2h, 2h+1, XOR-swizzled.
  int sg = (c32 >> 1) & 3;           // == ((wr|wc + i*32 + c32)>>1)&3 (wr,wc,32 mult of 32)
  int p0 = (2 * h) ^ sg, p1 = p0 ^ 1;
  int aIdx[2] = {(wr + c32) * 4, (wr + 32 + c32) * 4};
  int bIdx[2] = {(wc + c32) * 4, (wc + 32 + c32) * 4};

#define COMPUTE(b)                                                                   \
  do {                                                                               \
    const int4* Av = (const int4*)As[b];                                             \
    const int4* Bv = (const int4*)Bs[b];                                             \
    i32x8 af[2], bfr[2];                                                             \
    _Pragma("unroll") for (int i = 0; i < 2; i++) {                                  \
      int4 lo = Av[aIdx[i] + p0], hi = Av[aIdx[i] + p1];                             \
      af[i] = (i32x8){lo.x, lo.y, lo.z, lo.w, hi.x, hi.y, hi.z, hi.w};               \
    }                                                                                \
    _Pragma("unroll") for (int j = 0; j < 2; j++) {                                  \
      int4 lo = Bv[bIdx[j] + p0], hi = Bv[bIdx[j] + p1];                             \
      bfr[j] = (i32x8){lo.x, lo.y, lo.z, lo.w, hi.x, hi.y, hi.z, hi.w};              \
    }                                                                                \
    _Pragma("unroll") for (int i = 0; i < 2; i++)                                    \
      _Pragma("unroll") for (int j = 0; j < 2; j++)                                  \
        acc[i][j] = __builtin_amdgcn_mfma_scale_f32_32x32x64_f8f6f4(                 \
            af[i], bfr[j], acc[i][j], 0, 0, /*fp8,fp8*/                              \
            0, 0x7F, 0, 0x7F);            /* scales = 2^0 */                         \
  } while (0)

  STAGE(0);  // prologue: k-window 0
#pragma unroll
  for (int s = 0; s < 8; s += 2) {
    __syncthreads();           // drains window-s loads (in flight one full phase)
    if (s + 1 < 8) STAGE(1);   // issue window s+1 before computing s
    COMPUTE(0);
    __syncthreads();
    if (s + 2 < 8) STAGE(0);
    COMPUTE(1);
  }

  // ---- Epilogue. 32x32 C/D layout: col = lane&31, row = (reg&3)+8*(reg>>2)+4*h. ----
  bool isDiag = (tm == tn);
  bool hasPos = (tn == tm + 32);
  bool diagLane = (wr == wc) && (h == ((c32 >> 2) & 1));  // lane holding row==col elems
  int rsel = (c32 & 3) | ((c32 >> 3) << 2);               // reg with rowIn32 == c32

  if (isDiag && diagLane) {
    acc[0][0][rsel] = -1e30f;  // exp2 -> 0 (mask diagonal)
    acc[1][1][rsel] = -1e30f;
  }
  if (hasPos && diagLane) {
#pragma unroll
    for (int i = 0; i < 2; i++) {
      float sv = acc[i][i][rsel] * INV_TEMP;
      int gr = rowBase + wr + i * 32 + c32;
      posv[gr] = sv;            // unique (row,col) across grid -> race-free plain store
      posv[gr + HALF_N] = sv;   // sim symmetric
    }
  }

  float rp[32], cp[2] = {0.f, 0.f};
#pragma unroll
  for (int i = 0; i < 2; i++)
#pragma unroll
    for (int r = 0; r < 16; r++) {
      float e0 = __builtin_amdgcn_exp2f(acc[i][0][r] * E2SCALE);
      float e1 = __builtin_amdgcn_exp2f(acc[i][1][r] * E2SCALE);
      rp[i * 16 + r] = e0 + e1;
      cp[0] += e0;
      cp[1] += e1;
    }

  // Fold-reduce rp[32] across the 32-lane half; lane ends with v = c32 -> i=v>>4, reg=v&15.
#pragma unroll
  for (int t = 0; t < 16; t++) {
    float mine = (lane & 16) ? rp[t + 16] : rp[t];
    float oth = __shfl_xor((lane & 16) ? rp[t] : rp[t + 16], 16, 64);
    rp[t] = mine + oth;
  }
#pragma unroll
  for (int t = 0; t < 8; t++) {
    float mine = (lane & 8) ? rp[t + 8] : rp[t];
    float oth = __shfl_xor((lane & 8) ? rp[t] : rp[t + 8], 8, 64);
    rp[t] = mine + oth;
  }
#pragma unroll
  for (int t = 0; t < 4; t++) {
    float mine = (lane & 4) ? rp[t + 4] : rp[t];
    float oth = __shfl_xor((lane & 4) ? rp[t] : rp[t + 4], 4, 64);
    rp[t] = mine + oth;
  }
#pragma unroll
  for (int t = 0; t < 2; t++) {
    float mine = (lane & 2) ? rp[t + 2] : rp[t];
    float oth = __shfl_xor((lane & 2) ? rp[t] : rp[t + 2], 2, 64);
    rp[t] = mine + oth;
  }
  {
    float mine = (lane & 1) ? rp[1] : rp[0];
    float oth = __shfl_xor((lane & 1) ? rp[0] : rp[1], 1, 64);
    rp[0] = mine + oth;
  }
  // lane's row: i = c32>>4, reg = c32&15 -> rowIn32 = (c32&3) + 8*((c32>>2)&3) + 4*h
  int myrow = rowBase + wr + 32 * (c32 >> 4) + (c32 & 3) + 8 * ((c32 >> 2) & 3) + 4 * h;
  atomicAdd(&sumexp[myrow], rp[0]);

  if (!isDiag) {
    // col sums: sum the two k-halves' contributions, then lane h picks col-block j=h
    cp[0] += __shfl_xor(cp[0], 32, 64);
    cp[1] += __shfl_xor(cp[1], 32, 64);
    float cv = h ? cp[1] : cp[0];
    atomicAdd(&sumexp[colBase + wc + h * 32 + c32], cv);
  }
#undef STAGE
#undef COMPUTE
}

__global__ void __launch_bounds__(1024) k_final(const float* __restrict__ sumexp,
                                                const float* __restrict__ posv,
                                                float* __restrict__ out) {
  __shared__ float red[16];
  int tid = threadIdx.x;
  const float4* se4 = (const float4*)sumexp;
  const float4* pv4 = (const float4*)posv;
  float p = 0.f;
#pragma unroll
  for (int c = 0; c < 2; c++) {
    float4 se = se4[tid * 2 + c];
    float4 pv = pv4[tid * 2 + c];
    p += (__builtin_amdgcn_logf(se.x) + __builtin_amdgcn_logf(se.y) +
          __builtin_amdgcn_logf(se.z) + __builtin_amdgcn_logf(se.w)) * LN2 -
         (pv.x + pv.y + pv.z + pv.w);
  }
#pragma unroll
  for (int off = 32; off > 0; off >>= 1) p += __shfl_xor(p, off, 64);
  int wv = tid >> 6, ln = tid & 63;
  if (ln == 0) red[wv] = p;
  __syncthreads();
  if (tid == 0) {
    float t = 0.f;
    for (int w = 0; w < 16; w++) t += red[w];
    out[0] = t / (float)NROWS;
  }
}

extern "C" void kernel_launch(void* const* d_in, const int* in_sizes, int n_in,
                              void* d_out, int out_size, void* d_ws, size_t ws_size,
                              hipStream_t stream) {
  const float* zi = (const float*)d_in[0];
  const float* zj = (const float*)d_in[1];
  unsigned char* zn = (unsigned char*)d_ws;                           // 4 MB fp8
  float* sumexp = (float*)((char*)d_ws + (size_t)NROWS * DIM);        // 32 KB
  float* posv = sumexp + NROWS;                                       // 32 KB
  float* out = (float*)d_out;

  hipLaunchKernelGGL(k_normalize, dim3(2048), dim3(256), 0, stream, zi, zj, zn, sumexp);
  hipLaunchKernelGGL(k_simsum, dim3(NTILES), dim3(256), 0, stream, zn, sumexp, posv);
  hipLaunchKernelGGL(k_final, dim3(1), dim3(1024), 0, stream, sumexp, posv, out);
}